// Round 2
// baseline (702.937 us; speedup 1.0000x reference)
//
#include <hip/hip_runtime.h>
#include <hip/hip_bf16.h>
#include <stdint.h>

// AttentionReadout: fused per-graph kernel. fp32 I/O, bf16 MFMA compute.
// G=1024 graphs, N=64 nodes, D=512, H=8 heads, hd=64.
// One block (4 waves) per graph. All GEMMs in "A-rows @ B-rows^T" MFMA form.
// Pre-pass converts weights fp32->bf16 into d_ws (2 MB).

typedef __attribute__((ext_vector_type(8))) short short8;   // 8 bf16 (4 VGPRs)
typedef __attribute__((ext_vector_type(4))) float f32x4;    // MFMA C/D frag

#define H_  8
#define D_  512
#define N_  64

__device__ __forceinline__ unsigned short f2bf(float f) {
    union { float f; unsigned int u; } t; t.f = f;
    unsigned int u = t.u;
    return (unsigned short)((u + 0x7FFFu + ((u >> 16) & 1u)) >> 16);  // RNE
}

// ---- pre-pass: convert wqkv (786432 f) + wo (262144 f) -> bf16 in ws ----
__global__ __launch_bounds__(256)
void convert_weights(const float* __restrict__ wqkv, const float* __restrict__ wo,
                     unsigned short* __restrict__ wbf) {
    const int i4 = blockIdx.x * 256 + threadIdx.x;          // float4 index, 262144 total
    float4 v;
    if (i4 < 196608) v = *(const float4*)(wqkv + (size_t)i4 * 4);
    else             v = *(const float4*)(wo   + (size_t)(i4 - 196608) * 4);
    unsigned short a0 = f2bf(v.x), a1 = f2bf(v.y), a2 = f2bf(v.z), a3 = f2bf(v.w);
    uint2 p; p.x = a0 | ((unsigned)a1 << 16); p.y = a2 | ((unsigned)a3 << 16);
    *(uint2*)(wbf + (size_t)i4 * 4) = p;
}

__global__ __launch_bounds__(256, 2)
void attn_readout_kernel(const float* __restrict__ x,            // [65536,512] f32
                         const unsigned short* __restrict__ wqkv,// [1536,512] bf16 (ws)
                         const float* __restrict__ bqkv,         // [1536] f32
                         const unsigned short* __restrict__ wo,  // [512,512] bf16 (ws)
                         const float* __restrict__ bo,           // [512] f32
                         const float* __restrict__ gw,           // [512] f32
                         const float* __restrict__ gb,           // [1] f32
                         float* __restrict__ out)                // [G,512] f32
{
    __shared__ unsigned short xs[64][136];   // x slab [n][128 k + pad] (16B-aligned rows)
    __shared__ unsigned short qb[64][72];    // q [n][d]  -> later vT [d][n]
    __shared__ unsigned short kbuf[64][72];  // k [m][d]  -> later ctx [n][d]
    __shared__ unsigned short pb[64][72];    // P [n][m]
    __shared__ float red[4][64];
    __shared__ float gatev[64];

    const int g    = blockIdx.x;
    const int tid  = threadIdx.x;
    const int w    = tid >> 6;      // wave 0..3
    const int lane = tid & 63;
    const int l15  = lane & 15;
    const int quad = lane >> 4;     // 0..3

    // attn_out^T accumulators: wave w owns e in [w*128, w*128+128), n in [0,64)
    // oacc[et][nt]: e = w*128 + et*16 + quad*4 + r ; n = nt*16 + l15
    f32x4 oacc[8][4];
    #pragma unroll
    for (int et = 0; et < 8; ++et)
        #pragma unroll
        for (int nt = 0; nt < 4; ++nt)
            oacc[et][nt] = (f32x4){0.f, 0.f, 0.f, 0.f};

    for (int h = 0; h < H_; ++h) {
        // ---- QKV (swapped form): C'[d][n] = sum_k W[d][k] * x[n][k], K=512 ----
        f32x4 qacc[4], kacc[4], vacc[4];
        #pragma unroll
        for (int i = 0; i < 4; ++i) {
            qacc[i] = (f32x4){0.f,0.f,0.f,0.f};
            kacc[i] = (f32x4){0.f,0.f,0.f,0.f};
            vacc[i] = (f32x4){0.f,0.f,0.f,0.f};
        }
        const unsigned short* wqrow = wqkv + (size_t)(h*64 + w*16 + l15) * D_;

        for (int kb = 0; kb < 4; ++kb) {
            __syncthreads();  // xs safe to overwrite
            #pragma unroll
            for (int i = 0; i < 8; ++i) {       // 2048 float4 chunks / 256 thr
                int c4   = tid + i*256;
                int row  = c4 >> 5;
                int colf = (c4 & 31) << 2;
                float4 v = *(const float4*)(x + ((size_t)(g*64 + row))*D_ + kb*128 + colf);
                unsigned short a0 = f2bf(v.x), a1 = f2bf(v.y), a2 = f2bf(v.z), a3 = f2bf(v.w);
                uint2 p; p.x = a0 | ((unsigned)a1 << 16); p.y = a2 | ((unsigned)a3 << 16);
                *(uint2*)(&xs[row][colf]) = p;
            }
            __syncthreads();
            #pragma unroll
            for (int ks = 0; ks < 4; ++ks) {
                const int wcol = kb*128 + ks*32 + quad*8;
                short8 aq = *(const short8*)(wqrow + wcol);
                short8 ak = *(const short8*)(wqrow + (size_t)512*D_  + wcol);
                short8 av = *(const short8*)(wqrow + (size_t)1024*D_ + wcol);
                #pragma unroll
                for (int nt = 0; nt < 4; ++nt) {
                    short8 bx = *(const short8*)(&xs[nt*16 + l15][ks*32 + quad*8]);
                    qacc[nt] = __builtin_amdgcn_mfma_f32_16x16x32_bf16(aq, bx, qacc[nt], 0, 0, 0);
                    kacc[nt] = __builtin_amdgcn_mfma_f32_16x16x32_bf16(ak, bx, kacc[nt], 0, 0, 0);
                    vacc[nt] = __builtin_amdgcn_mfma_f32_16x16x32_bf16(av, bx, vacc[nt], 0, 0, 0);
                }
            }
        }

        // store q,k (+bias) to LDS [n][d]; lane value C'[d=w*16+quad*4+r][n=nt*16+l15]
        {
            const int dbase = h*64 + w*16 + quad*4;
            #pragma unroll
            for (int nt = 0; nt < 4; ++nt) {
                unsigned short tq[4], tk[4];
                #pragma unroll
                for (int r = 0; r < 4; ++r) {
                    tq[r] = f2bf(qacc[nt][r] + bqkv[dbase + r]);
                    tk[r] = f2bf(kacc[nt][r] + bqkv[512 + dbase + r]);
                }
                uint2 vq; vq.x = tq[0] | ((unsigned)tq[1] << 16); vq.y = tq[2] | ((unsigned)tq[3] << 16);
                uint2 vk; vk.x = tk[0] | ((unsigned)tk[1] << 16); vk.y = tk[2] | ((unsigned)tk[3] << 16);
                *(uint2*)(&qb  [nt*16 + l15][w*16 + quad*4]) = vq;
                *(uint2*)(&kbuf[nt*16 + l15][w*16 + quad*4]) = vk;
            }
        }
        __syncthreads();

        // ---- scores: S[n][m] = q.k^T / 8 ; wave w owns rows [w*16, w*16+16) ----
        f32x4 sacc[4];
        #pragma unroll
        for (int i = 0; i < 4; ++i) sacc[i] = (f32x4){0.f,0.f,0.f,0.f};
        #pragma unroll
        for (int ks = 0; ks < 2; ++ks) {
            short8 aq = *(const short8*)(&qb[w*16 + l15][ks*32 + quad*8]);
            #pragma unroll
            for (int mt = 0; mt < 4; ++mt) {
                short8 bk = *(const short8*)(&kbuf[mt*16 + l15][ks*32 + quad*8]);
                sacc[mt] = __builtin_amdgcn_mfma_f32_16x16x32_bf16(aq, bk, sacc[mt], 0, 0, 0);
            }
        }
        // softmax over m (64 cols); row n = w*16 + quad*4 + r
        float pv[4][4];
        #pragma unroll
        for (int r = 0; r < 4; ++r) {
            float m0 = -1e30f;
            #pragma unroll
            for (int mt = 0; mt < 4; ++mt) { pv[mt][r] = sacc[mt][r] * 0.125f; m0 = fmaxf(m0, pv[mt][r]); }
            m0 = fmaxf(m0, __shfl_xor(m0, 1));
            m0 = fmaxf(m0, __shfl_xor(m0, 2));
            m0 = fmaxf(m0, __shfl_xor(m0, 4));
            m0 = fmaxf(m0, __shfl_xor(m0, 8));
            float s = 0.f;
            #pragma unroll
            for (int mt = 0; mt < 4; ++mt) { float e = __expf(pv[mt][r] - m0); pv[mt][r] = e; s += e; }
            s += __shfl_xor(s, 1); s += __shfl_xor(s, 2); s += __shfl_xor(s, 4); s += __shfl_xor(s, 8);
            float inv = 1.0f / s;
            #pragma unroll
            for (int mt = 0; mt < 4; ++mt) pv[mt][r] *= inv;
        }
        #pragma unroll
        for (int mt = 0; mt < 4; ++mt)
            #pragma unroll
            for (int r = 0; r < 4; ++r)
                pb[w*16 + quad*4 + r][mt*16 + l15] = f2bf(pv[mt][r]);
        __syncthreads();  // P visible; all waves done reading qb (q dead)

        // store v^T (+bias) into qb: vT[d][n]
        {
            const int dbase = 1024 + h*64 + w*16 + quad*4;
            #pragma unroll
            for (int nt = 0; nt < 4; ++nt)
                #pragma unroll
                for (int r = 0; r < 4; ++r)
                    qb[w*16 + quad*4 + r][nt*16 + l15] = f2bf(vacc[nt][r] + bqkv[dbase + r]);
        }
        __syncthreads();  // vT visible

        // ---- ctx[n][d] = P @ v : A = P rows (strip w), B = vT rows, K=64 ----
        f32x4 cacc[4];
        #pragma unroll
        for (int i = 0; i < 4; ++i) cacc[i] = (f32x4){0.f,0.f,0.f,0.f};
        #pragma unroll
        for (int ks = 0; ks < 2; ++ks) {
            short8 ap = *(const short8*)(&pb[w*16 + l15][ks*32 + quad*8]);
            #pragma unroll
            for (int dt = 0; dt < 4; ++dt) {
                short8 bv = *(const short8*)(&qb[dt*16 + l15][ks*32 + quad*8]);
                cacc[dt] = __builtin_amdgcn_mfma_f32_16x16x32_bf16(ap, bv, cacc[dt], 0, 0, 0);
            }
        }
        // store ctx -> kbuf as [n][d] (k dead since scores)
        #pragma unroll
        for (int dt = 0; dt < 4; ++dt)
            #pragma unroll
            for (int r = 0; r < 4; ++r)
                kbuf[w*16 + quad*4 + r][dt*16 + l15] = f2bf(cacc[dt][r]);
        __syncthreads();  // ctx visible

        // ---- out-proj (swapped): attn_outT[e][n] += Wo[e][h*64+d] * ctx[n][d] ----
        #pragma unroll
        for (int ks = 0; ks < 2; ++ks) {
            short8 bc[4];
            #pragma unroll
            for (int nt = 0; nt < 4; ++nt)
                bc[nt] = *(const short8*)(&kbuf[nt*16 + l15][ks*32 + quad*8]);
            #pragma unroll
            for (int et = 0; et < 8; ++et) {
                const unsigned short* wop = wo + (size_t)(w*128 + et*16 + l15)*D_ + h*64 + ks*32 + quad*8;
                short8 aw = *(const short8*)wop;
                #pragma unroll
                for (int nt = 0; nt < 4; ++nt)
                    oacc[et][nt] = __builtin_amdgcn_mfma_f32_16x16x32_bf16(aw, bc[nt], oacc[et][nt], 0, 0, 0);
            }
        }
        // next head's first __syncthreads() protects all buffers
    }

    // ================= epilogue =================
    float gwf[8][4];
    #pragma unroll
    for (int et = 0; et < 8; ++et) {
        const int e0 = w*128 + et*16 + quad*4;
        #pragma unroll
        for (int r = 0; r < 4; ++r) {
            float obv = bo[e0 + r];
            gwf[et][r] = gw[e0 + r];
            #pragma unroll
            for (int nt = 0; nt < 4; ++nt) oacc[et][nt][r] += obv;
        }
    }
    // gate logits: gl[n] = sum_e attn_out[n][e]*gw[e]
    float pnt[4];
    #pragma unroll
    for (int nt = 0; nt < 4; ++nt) {
        float s = 0.f;
        #pragma unroll
        for (int et = 0; et < 8; ++et)
            #pragma unroll
            for (int r = 0; r < 4; ++r)
                s += oacc[et][nt][r] * gwf[et][r];
        s += __shfl_xor(s, 16);
        s += __shfl_xor(s, 32);
        pnt[nt] = s;  // partial over wave's 128 e's, for n = nt*16 + l15
    }
    if (lane < 16) {
        #pragma unroll
        for (int nt = 0; nt < 4; ++nt) red[w][nt*16 + lane] = pnt[nt];
    }
    __syncthreads();
    if (tid < 64) {
        float s = red[0][tid] + red[1][tid] + red[2][tid] + red[3][tid] + gb[0];
        gatev[tid] = 1.0f / (1.0f + __expf(-s));
    }
    __syncthreads();
    // out[g][e] = sum_n attn_out[n][e] * gate[n]
    #pragma unroll
    for (int et = 0; et < 8; ++et) {
        #pragma unroll
        for (int r = 0; r < 4; ++r) {
            float o = 0.f;
            #pragma unroll
            for (int nt = 0; nt < 4; ++nt)
                o += oacc[et][nt][r] * gatev[nt*16 + l15];
            o += __shfl_xor(o, 1); o += __shfl_xor(o, 2);
            o += __shfl_xor(o, 4); o += __shfl_xor(o, 8);
            if (l15 == 0)
                out[(size_t)g*D_ + w*128 + et*16 + quad*4 + r] = o;
        }
    }
}

extern "C" void kernel_launch(void* const* d_in, const int* in_sizes, int n_in,
                              void* d_out, int out_size, void* d_ws, size_t ws_size,
                              hipStream_t stream) {
    const float* x    = (const float*)d_in[0];
    // d_in[1] = batch (int) — unused: graphs are equal-sized (64 nodes)
    const float* wqkv = (const float*)d_in[2];
    const float* bqkv = (const float*)d_in[3];
    const float* wo   = (const float*)d_in[4];
    const float* bo   = (const float*)d_in[5];
    const float* gw   = (const float*)d_in[6];
    const float* gb   = (const float*)d_in[7];
    float* out = (float*)d_out;

    unsigned short* wbf = (unsigned short*)d_ws;          // 1048576 bf16 = 2 MB
    const unsigned short* wqkv_bf = wbf;                  // 786432
    const unsigned short* wo_bf   = wbf + 786432;         // 262144

    const int total = in_sizes[0] / D_;  // 65536 nodes
    const int G     = total / N_;        // 1024 graphs

    hipLaunchKernelGGL(convert_weights, dim3(1024), dim3(256), 0, stream, wqkv, wo, wbf);
    hipLaunchKernelGGL(attn_readout_kernel, dim3(G), dim3(256), 0, stream,
                       x, wqkv_bf, bqkv, wo_bf, bo, gw, gb, out);
}